// Round 3
// baseline (164.293 us; speedup 1.0000x reference)
//
#include <hip/hip_runtime.h>
#include <stdint.h>

// NonImagingRod: per-ray damped-Newton (LM) root find on f(t) = A t^2 + B t + C.
// Round-12: COALESCED loads via global_load_lds staging.
// R11 post-mortem: 8 independent chains per wave = NEUTRAL (43us, VALUBusy 45%)
// -> latency-exposure theory dead. Remaining consistent story: the wall is
// T_mem + T_compute additive, with the read path at only ~2.2 TB/s because the
// per-thread AoS float4 pattern has a 96B lane stride (64 distinct cache lines
// per vmem instr). The 6.29 TB/s copy ubench is lane-contiguous (16B stride).
// Fix: per-wave slab staging. Wave DMA-loads its contiguous 3KB P slab with
// 3x global_load_lds_dwordx4 (lane-contiguous!), ds_read_b128s its own rays,
// then REUSES the same LDS for the V slab. 4 rays/thread -> thread slab = 3
// quads exactly; ds_read stride 12 words -> 64 lanes x 4 words cover all 32
// banks 8x each = conflict-free (b128 wave64 floor), no padding needed (and
// global_load_lds requires a linear destination anyway).
// No __syncthreads: waves own disjoint LDS slices; intra-wave P->V buffer
// reuse ordered by one s_waitcnt lgkmcnt(0) (lockstep wave => all lanes' P
// reads retired before any V DMA is issued).
//
// Predicted: rod_kernel 43 -> 24-30us, VALUBusy 60-75%, LDS_BANK_CONFLICT ~0,
// FETCH stable ~49-50MB. If FLAT: coalescing theory dead; next = block-level
// de-phasing (loads of some blocks overlap compute of others).
//
// Codegen notes (hard-won, R2-R11):
//  - scalar iterate (6 fma + 1 rcp per ray) is the proven-clean shape; packed
//    v2f was neutral (didn't emit pk / marshalling ate it). Keep scalar.
//  - No-spill signature: FETCH_SIZE stable ~49-50 MB.
//  - Clamp(+-1000) provably inactive; rcp ~1ulp fine (absmax 0.0, R2-R11).

#define LM_ITERS 31
constexpr float DAMPING = 0.5f;

typedef __attribute__((address_space(3))) uint32_t lds_u32_t;
typedef __attribute__((address_space(1))) const uint32_t glob_u32_t;

__global__ __launch_bounds__(256) void rod_kernel(
    const float* __restrict__ P, const float* __restrict__ V,
    const float* __restrict__ Rm, const float* __restrict__ Tv,
    const float* __restrict__ c_ptr, double* __restrict__ ws, int n)
{
    const float c  = c_ptr[0];
    const float r00 = Rm[0], r01 = Rm[1], r02 = Rm[2];
    const float r10 = Rm[3], r11 = Rm[4], r12 = Rm[5];
    const float r20 = Rm[6], r21 = Rm[7], r22 = Rm[8];
    const float t0 = Tv[0], t1 = Tv[1], t2 = Tv[2];

    // Per-wave staging slab: 4 waves x 192 quads (3 KB each) = 12 KB/block.
    __shared__ float4 sh[4][192];

    const int lane = threadIdx.x & 63;
    const int wave = threadIdx.x >> 6;
    // wave owns 256 consecutive rays; lane owns 4 consecutive rays.
    const int wave_ray_base = blockIdx.x * 1024 + wave * 256;
    const int base_ray      = wave_ray_base + 4 * lane;

    float px[4], py[4], pz[4], wx[4], wy[4], wz[4];

    if (wave_ray_base + 256 <= n) {
        // ---- fast path: whole-slab DMA staging (lane-contiguous global) ----
        // wave's P slab starts at quad index wave_ray_base*3/4 (rays are
        // multiples of 256, so *3/4 is exact).
        const size_t wq = (size_t)(wave_ray_base >> 2) * 3;
        const char* gP = (const char*)P + wq * 16;
        const char* gV = (const char*)V + wq * 16;

        // stage P: 3 x (64 lanes x 16 B) = 3 KB, linear into sh[wave]
        #pragma unroll
        for (int j = 0; j < 3; ++j) {
            __builtin_amdgcn_global_load_lds(
                (glob_u32_t*)(gP + (size_t)(j * 64 + lane) * 16),
                (lds_u32_t*)&sh[wave][j * 64 + lane], 16, 0, 0);
        }
        asm volatile("s_waitcnt vmcnt(0)" ::: "memory");
        const float4 pa = sh[wave][lane * 3 + 0];
        const float4 pb = sh[wave][lane * 3 + 1];
        const float4 pc = sh[wave][lane * 3 + 2];
        // all lanes' P reads must retire before V DMA overwrites the slab
        asm volatile("s_waitcnt lgkmcnt(0)" ::: "memory");

        // stage V into the same slots
        #pragma unroll
        for (int j = 0; j < 3; ++j) {
            __builtin_amdgcn_global_load_lds(
                (glob_u32_t*)(gV + (size_t)(j * 64 + lane) * 16),
                (lds_u32_t*)&sh[wave][j * 64 + lane], 16, 0, 0);
        }
        asm volatile("s_waitcnt vmcnt(0)" ::: "memory");
        const float4 va = sh[wave][lane * 3 + 0];
        const float4 vb = sh[wave][lane * 3 + 1];
        const float4 vc = sh[wave][lane * 3 + 2];
        asm volatile("s_waitcnt lgkmcnt(0)" ::: "memory");

        // unpack 3 quads -> 4 rays: words [x0 y0 z0 x1][y1 z1 x2 y2][z2 x3 y3 z3]
        px[0] = pa.x; px[1] = pa.w; px[2] = pb.z; px[3] = pc.y;
        py[0] = pa.y; py[1] = pb.x; py[2] = pb.w; py[3] = pc.z;
        pz[0] = pa.z; pz[1] = pb.y; pz[2] = pc.x; pz[3] = pc.w;
        wx[0] = va.x; wx[1] = va.w; wx[2] = vb.z; wx[3] = vc.y;
        wy[0] = va.y; wy[1] = vb.x; wy[2] = vb.w; wy[3] = vc.z;
        wz[0] = va.z; wz[1] = vb.y; wz[2] = vc.x; wz[3] = vc.w;
    } else {
        // ---- tail fallback: guarded scalar loads (not hit for n = 4M) ----
        #pragma unroll
        for (int r = 0; r < 4; ++r) {
            const int ray = base_ray + r;
            if (ray < n) {
                px[r] = P[3 * ray + 0]; py[r] = P[3 * ray + 1]; pz[r] = P[3 * ray + 2];
                wx[r] = V[3 * ray + 0]; wy[r] = V[3 * ray + 1]; wz[r] = V[3 * ray + 2];
            } else {
                px[r] = py[r] = pz[r] = 0.0f;
                wx[r] = wy[r] = wz[r] = 0.0f;
            }
        }
    }

    // ---- per-ray setup: rigid inverse transform, quadratic coefficients ----
    float nA[4], f[4], fp[4];
    #pragma unroll
    for (int r = 0; r < 4; ++r) {
        const float qx = px[r] - t0, qy = py[r] - t1, qz = pz[r] - t2;
        const float plx = qx * r00 + qy * r10 + qz * r20;
        const float ply = qx * r01 + qy * r11 + qz * r21;
        const float plz = qx * r02 + qy * r12 + qz * r22;
        const float vlx = wx[r] * r00 + wy[r] * r10 + wz[r] * r20;
        const float vly = wx[r] * r01 + wy[r] * r11 + wz[r] * r21;
        const float vlz = wx[r] * r02 + wy[r] * r12 + wz[r] * r22;
        nA[r] = c * (vly * vly + vlz * vlz);                 // -A
        f[r]  = plx - c * (ply * ply + plz * plz);           // f(0)  = C
        fp[r] = vlx - 2.0f * c * (ply * vly + plz * vlz);    // f'(0) = B
    }

    // delta = f*f'/(f'^2+damping); tmp = f' - A*delta;
    // f <- f - delta*tmp (exact quadratic); f' <- tmp - A*delta.
    #pragma unroll 1
    for (int it = 0; it < LM_ITERS; ++it) {
        #pragma unroll
        for (int r = 0; r < 4; ++r) {
            const float den = fmaf(fp[r], fp[r], DAMPING);
            const float rcp = __builtin_amdgcn_rcpf(den);  // ~1 ulp; LM self-corrects
            const float d   = (f[r] * fp[r]) * rcp;
            const float tmp = fmaf(nA[r], d, fp[r]);
            f[r]  = fmaf(-d, tmp, f[r]);
            fp[r] = fmaf(nA[r], d, tmp);
        }
    }

    // ---- accumulate sum of f^2 over this thread's 4 rays (f64) ----
    double acc = 0.0;
    #pragma unroll
    for (int r = 0; r < 4; ++r)
        if (base_ray + r < n) acc += (double)f[r] * (double)f[r];

    // wave(64) shuffle reduce -> LDS across 4 waves -> one f64 atomic per block
    for (int off = 32; off > 0; off >>= 1)
        acc += __shfl_down(acc, off, 64);
    __shared__ double sacc[4];
    if (lane == 0) sacc[wave] = acc;
    __syncthreads();
    if (threadIdx.x == 0) {
        atomicAdd(ws, sacc[0] + sacc[1] + sacc[2] + sacc[3]);
    }
}

__global__ void rod_finalize(const double* __restrict__ ws,
                             const float* __restrict__ loss_in,
                             float* __restrict__ out, double inv_n)
{
    out[0] = (float)(ws[0] * inv_n + (double)loss_in[0]);
}

extern "C" void kernel_launch(void* const* d_in, const int* in_sizes, int n_in,
                              void* d_out, int out_size, void* d_ws, size_t ws_size,
                              hipStream_t stream) {
    const float* P       = (const float*)d_in[0];
    const float* V       = (const float*)d_in[1];
    const float* R       = (const float*)d_in[2];
    const float* T       = (const float*)d_in[3];
    const float* c       = (const float*)d_in[4];
    const float* loss_in = (const float*)d_in[5];

    const int n = in_sizes[0] / 3;           // number of rays

    // d_ws is poisoned to 0xAA before every launch — zero the accumulator.
    hipMemsetAsync(d_ws, 0, sizeof(double), stream);

    // 4 rays/thread, 1024 rays/block -> 4096 blocks for n=4M.
    // LDS 12 KB/block: caps at 8 blocks/CU (wave limit), 2 dispatch rounds.
    const int threads = (n + 3) / 4;
    const int block   = 256;
    const int grid    = (threads + block - 1) / block;
    rod_kernel<<<grid, block, 0, stream>>>(P, V, R, T, c, (double*)d_ws, n);
    rod_finalize<<<1, 1, 0, stream>>>((const double*)d_ws, loss_in,
                                      (float*)d_out, 1.0 / (double)n);
}

// Round 4
// 137.615 us; speedup vs baseline: 1.1939x; 1.1939x over previous
//
#include <hip/hip_runtime.h>

// NonImagingRod: per-ray damped-Newton (LM) root find on f(t) = A t^2 + B t + C.
// Round-13: PERFECT COALESCING with zero redistribution, via strided ray->lane
// mapping + float3 loads.
// R12 post-mortem: DMA staging lost (65us) because it destroyed per-wave MLP
// (3 outstanding loads + full vmcnt(0) drains) -- it never cleanly tested
// coalescing. R10 explained: 157.3 TF fp32 spec = plain wave64 FMA rate; no
// double-rate packed fp32 on gfx950, so packed math couldn't help.
// Surviving model: wall 43us = ~20us VALU issue (invariant across R8-R12,
// = VALUBusy x dur) + ~23us memory at ~2.2 TB/s effective. Blocked AoS float4
// loads have 48B lane stride -> 48 lines per 1KB wave-instr = 3x compulsory
// transactions (~4.5M line-requests vs 1.5M).
// Fix: rays are independent, reduction symmetric -> ray->lane map is FREE.
// ray = wave_base + 64*r + lane, loaded as float3 (12B): each wave instr reads
// a 768B fully-contiguous window (12 lines, all bytes consumed). Perfect
// coalescing, compulsory-only transactions, data lands in the right lane.
// No LDS, no shuffles, same proven R11 compute structure (8 rays/thread,
// 8 independent chains, single chunk).
//
// Predicted: rod_kernel 43 -> 30-36us, VALUBusy -> 55-65%, FETCH ~49-50MB.
// If FLAT: pattern theory dead -> latency*concurrency ceiling; accept or
// attack phase overlap next.
//
// Codegen notes (hard-won, R2-R12):
//  - scalar iterate (4 fma + 2 mul + 1 rcp per ray) is the proven shape.
//  - No-spill signature: FETCH_SIZE stable ~49-50 MB.
//  - Clamp(+-1000) provably inactive; rcp ~1ulp fine (absmax 0.0, R2-R12).
//  - f64 accumulate per-thread -> wave shuffle -> LDS -> one atomic per block;
//    grouping/order changes have stayed absmax 0.0 across all rounds.

#define LM_ITERS 31
constexpr float DAMPING = 0.5f;

struct F3 { float x, y, z; };   // 12B, 4-aligned -> global_load_dwordx3

__global__ __launch_bounds__(256) void rod_kernel(
    const float* __restrict__ P, const float* __restrict__ V,
    const float* __restrict__ Rm, const float* __restrict__ Tv,
    const float* __restrict__ c_ptr, double* __restrict__ ws, int n)
{
    const float c  = c_ptr[0];
    const float r00 = Rm[0], r01 = Rm[1], r02 = Rm[2];
    const float r10 = Rm[3], r11 = Rm[4], r12 = Rm[5];
    const float r20 = Rm[6], r21 = Rm[7], r22 = Rm[8];
    const float t0 = Tv[0], t1 = Tv[1], t2 = Tv[2];

    const int lane = threadIdx.x & 63;
    const int wave = threadIdx.x >> 6;
    // wave owns 512 consecutive rays; lane's 8 rays are STRIDED through the
    // window so each load instr is lane-contiguous (12B stride = consecutive
    // float3 rays = 768B window).
    const int wbase = (blockIdx.x * 4 + wave) * 512;

    const F3* __restrict__ P3 = (const F3*)P;
    const F3* __restrict__ V3 = (const F3*)V;

    float px[8], py[8], pz[8], qx[8], qy[8], qz[8];

    if (wbase + 512 <= n) {
        // fast path: 16 x dwordx3, all in flight together (full MLP)
        #pragma unroll
        for (int r = 0; r < 8; ++r) {
            const int ray = wbase + 64 * r + lane;
            const F3 p = P3[ray];
            px[r] = p.x; py[r] = p.y; pz[r] = p.z;
        }
        #pragma unroll
        for (int r = 0; r < 8; ++r) {
            const int ray = wbase + 64 * r + lane;
            const F3 v = V3[ray];
            qx[r] = v.x; qy[r] = v.y; qz[r] = v.z;
        }
    } else {
        // tail fallback (not hit for n = 4M): guarded scalar loads
        #pragma unroll
        for (int r = 0; r < 8; ++r) {
            const int ray = wbase + 64 * r + lane;
            if (ray < n) {
                px[r] = P[3 * ray + 0]; py[r] = P[3 * ray + 1]; pz[r] = P[3 * ray + 2];
                qx[r] = V[3 * ray + 0]; qy[r] = V[3 * ray + 1]; qz[r] = V[3 * ray + 2];
            } else {
                px[r] = py[r] = pz[r] = 0.0f;
                qx[r] = qy[r] = qz[r] = 0.0f;
            }
        }
    }

    // ---- per-ray setup: rigid inverse transform, quadratic coefficients ----
    float nA[8], f[8], fp[8];
    #pragma unroll
    for (int r = 0; r < 8; ++r) {
        const float ax = px[r] - t0, ay = py[r] - t1, az = pz[r] - t2;
        const float plx = ax * r00 + ay * r10 + az * r20;
        const float ply = ax * r01 + ay * r11 + az * r21;
        const float plz = ax * r02 + ay * r12 + az * r22;
        const float vlx = qx[r] * r00 + qy[r] * r10 + qz[r] * r20;
        const float vly = qx[r] * r01 + qy[r] * r11 + qz[r] * r21;
        const float vlz = qx[r] * r02 + qy[r] * r12 + qz[r] * r22;
        nA[r] = c * (vly * vly + vlz * vlz);                 // -A
        f[r]  = plx - c * (ply * ply + plz * plz);           // f(0)  = C
        fp[r] = vlx - 2.0f * c * (ply * vly + plz * vlz);    // f'(0) = B
    }

    // delta = f*f'/(f'^2+damping); tmp = f' - A*delta;
    // f <- f - delta*tmp (exact quadratic); f' <- tmp - A*delta.
    // 8 independent chains per iteration.
    #pragma unroll 1
    for (int it = 0; it < LM_ITERS; ++it) {
        #pragma unroll
        for (int r = 0; r < 8; ++r) {
            const float den = fmaf(fp[r], fp[r], DAMPING);
            const float rcp = __builtin_amdgcn_rcpf(den);  // ~1 ulp; LM self-corrects
            const float d   = (f[r] * fp[r]) * rcp;
            const float tmp = fmaf(nA[r], d, fp[r]);
            f[r]  = fmaf(-d, tmp, f[r]);
            fp[r] = fmaf(nA[r], d, tmp);
        }
    }

    // ---- accumulate sum of f^2 over this thread's 8 rays (f64) ----
    double acc = 0.0;
    #pragma unroll
    for (int r = 0; r < 8; ++r)
        if (wbase + 64 * r + lane < n) acc += (double)f[r] * (double)f[r];

    // wave(64) shuffle reduce -> LDS across 4 waves -> one f64 atomic per block
    for (int off = 32; off > 0; off >>= 1)
        acc += __shfl_down(acc, off, 64);
    __shared__ double sacc[4];
    if (lane == 0) sacc[wave] = acc;
    __syncthreads();
    if (threadIdx.x == 0) {
        atomicAdd(ws, sacc[0] + sacc[1] + sacc[2] + sacc[3]);
    }
}

__global__ void rod_finalize(const double* __restrict__ ws,
                             const float* __restrict__ loss_in,
                             float* __restrict__ out, double inv_n)
{
    out[0] = (float)(ws[0] * inv_n + (double)loss_in[0]);
}

extern "C" void kernel_launch(void* const* d_in, const int* in_sizes, int n_in,
                              void* d_out, int out_size, void* d_ws, size_t ws_size,
                              hipStream_t stream) {
    const float* P       = (const float*)d_in[0];
    const float* V       = (const float*)d_in[1];
    const float* R       = (const float*)d_in[2];
    const float* T       = (const float*)d_in[3];
    const float* c       = (const float*)d_in[4];
    const float* loss_in = (const float*)d_in[5];

    const int n = in_sizes[0] / 3;           // number of rays

    // d_ws is poisoned to 0xAA before every launch — zero the accumulator.
    hipMemsetAsync(d_ws, 0, sizeof(double), stream);

    // 8 rays/thread, 512 rays/wave (strided within the wave window).
    // 2048 blocks = 8 blocks/CU = whole grid co-resident in one round.
    const int threads = (n + 7) / 8;
    const int block   = 256;
    const int grid    = (threads + block - 1) / block;
    rod_kernel<<<grid, block, 0, stream>>>(P, V, R, T, c, (double*)d_ws, n);
    rod_finalize<<<1, 1, 0, stream>>>((const double*)d_ws, loss_in,
                                      (float*)d_out, 1.0 / (double)n);
}